// Round 3
// baseline (13708.817 us; speedup 1.0000x reference)
//
#include <hip/hip_runtime.h>

#define cB 16
#define cS 512
#define cD 512
#define cL 64
#define cG 8     // blocks per batch
#define cT 512   // threads per block

// ---------------- workspace layout (bytes) ----------------
constexpr size_t FCOPY   = (size_t)cB * cS * cD * 4;            // 16 MB per F copy
constexpr size_t OFF_F0  = 0;
constexpr size_t OFF_F1  = FCOPY;
constexpr size_t OFF_U   = 2 * FCOPY;                           // D f32
constexpr size_t OFF_V   = OFF_U  + 2048;
constexpr size_t OFF_UA  = OFF_V  + 2048;                       // W1a @ u
constexpr size_t OFF_UB  = OFF_UA + 2048;                       // W1b @ u
constexpr size_t OFF_VA  = OFF_UB + 2048;                       // W1a @ v
constexpr size_t OFF_VB  = OFF_VA + 2048;                       // W1b @ v
constexpr size_t OFF_SC  = OFF_VB + 2048;                       // [c0, cu, cv]
constexpr size_t OFF_SI  = OFF_SC + 64;                         // B*S f32
constexpr size_t OFF_SJ  = OFF_SI + (size_t)cB*cS*4;
constexpr size_t OFF_CLS = OFF_SJ + (size_t)cB*cS*4;
constexpr size_t OFF_ADJ = OFF_CLS+ (size_t)cB*cS*4;            // B*S*8 u64 (row-major)
constexpr size_t OFF_RM  = OFF_ADJ+ (size_t)cB*cS*64;
constexpr size_t OFF_RA  = OFF_RM + (size_t)cB*cS*4;
constexpr size_t OFF_BAR = ((OFF_RA + (size_t)cB*cS*4 + 127) & ~(size_t)127);  // B*128B

// ---------------- K1: u = W1a@w2, v = W1b@w2, c0 = b1@w2 + b2 ----------------
__global__ void k1_uvc(const float* __restrict__ W1, const float* __restrict__ b1,
                       const float* __restrict__ w2, const float* __restrict__ b2,
                       char* __restrict__ ws) {
    const int t = threadIdx.x;
    const int r = blockIdx.x;
    if (r == 1025) {   // zero barrier counters (ws poisoned 0xAA pre-launch)
        unsigned* bar = (unsigned*)(ws + OFF_BAR);
        bar[t] = 0u; bar[t + 256] = 0u;
        return;
    }
    __shared__ float rs[256];
    float acc;
    if (r < 1024) {
        const float* row = W1 + (size_t)r * cD;
        acc = row[t] * w2[t] + row[t + 256] * w2[t + 256];
    } else {
        acc = b1[t] * w2[t] + b1[t + 256] * w2[t + 256];
    }
    rs[t] = acc; __syncthreads();
    for (int o = 128; o; o >>= 1) { if (t < o) rs[t] += rs[t + o]; __syncthreads(); }
    if (t == 0) {
        if (r < 512)        ((float*)(ws + OFF_U))[r] = rs[0];
        else if (r < 1024)  ((float*)(ws + OFF_V))[r - 512] = rs[0];
        else                ((float*)(ws + OFF_SC))[0] = rs[0] + b2[0];   // c0
    }
}

// ---------------- K1b: ua/ub/va/vb = W1{a,b} @ {u,v};  cu = b1·u, cv = b1·v --------
__global__ void k1b_proj(const float* __restrict__ W1, const float* __restrict__ b1,
                         char* __restrict__ ws) {
    __shared__ float ru[256], rv[256];
    const int t = threadIdx.x;
    const int k = blockIdx.x;
    const float* U = (const float*)(ws + OFF_U);
    const float* V = (const float*)(ws + OFF_V);
    const float* row = (k < 1024) ? (W1 + (size_t)k * cD) : b1;
    ru[t] = row[t] * U[t] + row[t + 256] * U[t + 256];
    rv[t] = row[t] * V[t] + row[t + 256] * V[t + 256];
    __syncthreads();
    for (int o = 128; o; o >>= 1) {
        if (t < o) { ru[t] += ru[t + o]; rv[t] += rv[t + o]; }
        __syncthreads();
    }
    if (t == 0) {
        if (k < 512)       { ((float*)(ws + OFF_UA))[k] = ru[0]; ((float*)(ws + OFF_VA))[k] = rv[0]; }
        else if (k < 1024) { ((float*)(ws + OFF_UB))[k - 512] = ru[0]; ((float*)(ws + OFF_VB))[k - 512] = rv[0]; }
        else               { ((float*)(ws + OFF_SC))[1] = ru[0]; ((float*)(ws + OFF_SC))[2] = rv[0]; }
    }
}

// ---------------- K2: gather feats into F copy0, si = f@u, sj = f@v ----------------
__global__ void k2_feat(const int* __restrict__ tok, const float* __restrict__ emb,
                        char* __restrict__ ws) {
    __shared__ float ru[256], rv[256];
    const int t = threadIdx.x;
    const int bs = blockIdx.x;
    const float* U = (const float*)(ws + OFF_U);
    const float* V = (const float*)(ws + OFF_V);
    float* F = (float*)(ws + OFF_F0);
    const int tk = tok[bs];
    const float* src = emb + (size_t)tk * cD;
    float* dst = F + (size_t)bs * cD;
    const float e0 = src[t], e1 = src[t + 256];
    dst[t] = e0; dst[t + 256] = e1;
    ru[t] = e0 * U[t] + e1 * U[t + 256];
    rv[t] = e0 * V[t] + e1 * V[t + 256];
    __syncthreads();
    for (int o = 128; o; o >>= 1) {
        if (t < o) { ru[t] += ru[t + o]; rv[t] += rv[t + o]; }
        __syncthreads();
    }
    if (t == 0) {
        ((float*)(ws + OFF_SI))[bs] = ru[0];
        ((float*)(ws + OFF_SJ))[bs] = rv[0];
    }
}

// ---------------- K3: logits argmax -> cls ----------------
__global__ void k3_cls(const float* __restrict__ posW, const float* __restrict__ posb,
                       char* __restrict__ ws) {
    const int t = threadIdx.x;            // one wave
    const int bs = blockIdx.x;
    const float* frow = (const float*)(ws + OFF_F0) + (size_t)bs * cD;
    float acc = posb[t];
    for (int k = 0; k < cD; k++) acc += frow[k] * posW[(size_t)k * cL + t];
    int idx = t;
    for (int off = 32; off; off >>= 1) {
        float ov = __shfl_down(acc, off, 64);
        int   oi = __shfl_down(idx, off, 64);
        if (ov > acc || (ov == acc && oi < idx)) { acc = ov; idx = oi; }
    }
    if (t == 0) ((int*)(ws + OFF_CLS))[bs] = idx;
}

// ---------------- K4: adjacency bitmask + initial per-row max ----------------
__global__ void k4_adj(char* __restrict__ ws) {
    __shared__ float rsv[256]; __shared__ int rsk[256];
    const int t = threadIdx.x;
    const int bs = blockIdx.x;
    const int b = bs >> 9, r = bs & 511;
    const int* cls = (const int*)(ws + OFF_CLS) + (size_t)b * cS;
    const float* SJ = (const float*)(ws + OFF_SJ) + (size_t)b * cS;
    const float sir = ((const float*)(ws + OFF_SI))[bs];
    const float c0 = ((const float*)(ws + OFF_SC))[0];
    unsigned long long* adjrow = (unsigned long long*)(ws + OFF_ADJ) + (size_t)bs * 8;
    const int cr = cls[r];
    float bv = -INFINITY; int bc = 0;
    for (int p = 0; p < 2; p++) {
        const int c = p * 256 + t;
        int dd = c - r; if (dd < 0) dd = -dd;
        const bool allowed = (c != r) && (dd == 1 || cls[c] == cr);
        unsigned long long m = __ballot(allowed);
        if ((t & 63) == 0) adjrow[p * 4 + (t >> 6)] = m;
        if (allowed) {
            float val = sir + SJ[c] + c0;
            if (val > bv || (val == bv && c < bc)) { bv = val; bc = c; }
        }
    }
    rsv[t] = bv; rsk[t] = bc; __syncthreads();
    for (int o = 128; o; o >>= 1) {
        if (t < o) {
            float s2 = rsv[t + o]; int k2 = rsk[t + o];
            if (s2 > rsv[t] || (s2 == rsv[t] && k2 < rsk[t])) { rsv[t] = s2; rsk[t] = k2; }
        }
        __syncthreads();
    }
    if (t == 0) { ((float*)(ws + OFF_RM))[bs] = rsv[0]; ((int*)(ws + OFF_RA))[bs] = rsk[0]; }
}

// ---------------- K5: parser — replicated LDS state, 1 split-phase barrier/step ------
__global__ void __launch_bounds__(cT, 2)
parse_main(const float* __restrict__ W1, const float* __restrict__ b1,
           char* __restrict__ ws, float* __restrict__ out) {
    const int t = threadIdx.x;
    const int b = blockIdx.x & 15;        // batch (same XCD for a batch's 8 blocks)
    const int g = blockIdx.x >> 4;        // 0..7
    const int d0 = g * 64;

    unsigned long long* F64[2] = {
        (unsigned long long*)(ws + OFF_F0) + (size_t)b * cS * cD / 2,
        (unsigned long long*)(ws + OFF_F1) + (size_t)b * cS * cD / 2 };
    unsigned* barcnt = (unsigned*)(ws + OFF_BAR) + (size_t)b * 32;
    const float* SCp = (const float*)(ws + OFF_SC);
    const float c0 = SCp[0], cu = SCp[1], cv = SCp[2];

    // replicated per-block state
    __shared__ unsigned long long AdjL[8 * 512];   // column-major: AdjL[w*512 + r]
    __shared__ float SIl[512], SJl[512], rmax[512];
    __shared__ int   rarg[512];
    __shared__ unsigned char par[512];             // F-copy parity per row
    __shared__ float xls[1024];                    // [fi(512); fj(512)]
    __shared__ float rsh[512];
    __shared__ float wsv[8];  __shared__ int wsk[8];
    __shared__ float ws_si[8], ws_sj[8];
    __shared__ int   s_bi, s_bj; __shared__ float s_bv, s_sin, s_sjn;
    __shared__ int   rescanList[516]; __shared__ int nresc;

    // W1 slice in registers: thread (ks=t>>6, od=t&63) holds W1[ks*128 .. +127][d0+od]
    const int ks = t >> 6, od = t & 63, kbase = ks * 128;
    float w[128];
#pragma unroll
    for (int kk = 0; kk < 128; kk++) w[kk] = W1[(size_t)(kbase + kk) * cD + d0 + od];

    // replicated init
    SIl[t]  = ((const float*)(ws + OFF_SI))[b * cS + t];
    SJl[t]  = ((const float*)(ws + OFF_SJ))[b * cS + t];
    rmax[t] = ((const float*)(ws + OFF_RM))[b * cS + t];
    rarg[t] = ((const int*)(ws + OFF_RA))[b * cS + t];
    par[t]  = 0;
    const float rua = ((const float*)(ws + OFF_UA))[t];
    const float rub = ((const float*)(ws + OFF_UB))[t];
    const float rva = ((const float*)(ws + OFF_VA))[t];
    const float rvb = ((const float*)(ws + OFF_VB))[t];
    float b1a = 0.f, b1b = 0.f;
    if (t < 32) { b1a = b1[d0 + 2 * t]; b1b = b1[d0 + 2 * t + 1]; }
    {
        const unsigned long long* AG =
            (const unsigned long long*)(ws + OFF_ADJ) + (size_t)b * cS * 8;
#pragma unroll
        for (int wq = 0; wq < 8; wq++) AdjL[wq * 512 + t] = AG[(size_t)t * 8 + wq];
    }
    bool myAlive = true;
    float tot = 0.f;
    __syncthreads();

    for (int it = 0; it < cS - 1; ++it) {
        // ---- A: replicated global argmax (LDS only) ----
        {
            float av = rmax[t]; int ak = (t << 9) | rarg[t];
#pragma unroll
            for (int off = 32; off; off >>= 1) {
                float ov = __shfl_down(av, off, 64);
                int   ok = __shfl_down(ak, off, 64);
                if (ov > av || (ov == av && ok < ak)) { av = ov; ak = ok; }
            }
            if ((t & 63) == 0) { wsv[t >> 6] = av; wsk[t >> 6] = ak; }
        }
        __syncthreads();
        if (t < 64) {
            float fv = (t < 8) ? wsv[t] : -INFINITY;
            int   fk = (t < 8) ? wsk[t] : 0x7fffffff;
#pragma unroll
            for (int off = 4; off; off >>= 1) {
                float ov = __shfl_down(fv, off, 64);
                int   ok = __shfl_down(fk, off, 64);
                if (ov > fv || (ov == fv && ok < fk)) { fv = ov; fk = ok; }
            }
            if (t == 0) { s_bv = fv; s_bi = fk >> 9; s_bj = fk & 511; }
        }
        // ---- wait-phase of split barrier: all parent stores of step it-1 visible ----
        if (t == 0) {
            const unsigned tgt = 8u * (unsigned)it;
            while (__hip_atomic_load(barcnt, __ATOMIC_RELAXED, __HIP_MEMORY_SCOPE_AGENT) < tgt)
                __builtin_amdgcn_s_sleep(1);
        }
        __syncthreads();
        const int bi = s_bi, bj = s_bj;
        if (g == 0 && t == 0) {
            tot += s_bv;
            out[16 + b * 1022 + it * 2 + 0] = (float)bi;
            out[16 + b * 1022 + it * 2 + 1] = (float)bj;
        }

        // ---- C: load fi/fj (sc1 atomics from current copies), matvec, store slice ----
        const int pi = par[bi], pj = par[bj];
        if (t < 256) {
            unsigned long long x = __hip_atomic_load(F64[pi] + (size_t)bi * 256 + t,
                                    __ATOMIC_RELAXED, __HIP_MEMORY_SCOPE_AGENT);
            float2 f; __builtin_memcpy(&f, &x, 8);
            xls[2 * t] = f.x; xls[2 * t + 1] = f.y;
        } else {
            const int tt = t - 256;
            unsigned long long x = __hip_atomic_load(F64[pj] + (size_t)bj * 256 + tt,
                                    __ATOMIC_RELAXED, __HIP_MEMORY_SCOPE_AGENT);
            float2 f; __builtin_memcpy(&f, &x, 8);
            xls[512 + 2 * tt] = f.x; xls[513 + 2 * tt] = f.y;
        }
        __syncthreads();

        // sin/sjn contributions (identical in all blocks) + W1 matvec partials
        {
            float csi = xls[t] * rua + xls[512 + t] * rub;
            float csj = xls[t] * rva + xls[512 + t] * rvb;
#pragma unroll
            for (int off = 32; off; off >>= 1) {
                csi += __shfl_down(csi, off, 64);
                csj += __shfl_down(csj, off, 64);
            }
            if ((t & 63) == 0) { ws_si[t >> 6] = csi; ws_sj[t >> 6] = csj; }
        }
        float acc = 0.f;
#pragma unroll
        for (int kk = 0; kk < 128; kk++) acc += w[kk] * xls[kbase + kk];
        rsh[t] = acc;
        __syncthreads();
        if (t < 32) {
            float p0 = b1a, p1 = b1b;
#pragma unroll
            for (int q = 0; q < 8; q++) { p0 += rsh[q * 64 + 2 * t]; p1 += rsh[q * 64 + 2 * t + 1]; }
            float2 pp; pp.x = p0; pp.y = p1;
            unsigned long long pk; __builtin_memcpy(&pk, &pp, 8);
            __hip_atomic_store(F64[pi ^ 1] + (size_t)bi * 256 + g * 32 + t, pk,
                               __ATOMIC_RELAXED, __HIP_MEMORY_SCOPE_AGENT);
        }
        if (t < 64) {
            float su = (t < 8) ? ws_si[t] : 0.f;
            float sv = (t < 8) ? ws_sj[t] : 0.f;
#pragma unroll
            for (int off = 4; off; off >>= 1) {
                su += __shfl_down(su, off, 64);
                sv += __shfl_down(sv, off, 64);
            }
            if (t == 0) {
                const float sn = su + cu, jn = sv + cv;
                s_sin = sn; s_sjn = jn;
                SIl[bi] = sn; SJl[bi] = jn;
                par[bi] ^= 1;
                nresc = 0;
            }
        }
        // ---- arrive-phase: drain own sc1 stores, then bump counter ----
        asm volatile("s_waitcnt vmcnt(0)" ::: "memory");
        __syncthreads();
        if (t == 0) __hip_atomic_fetch_add(barcnt, 1u, __ATOMIC_RELAXED, __HIP_MEMORY_SCOPE_AGENT);

        // ---- D: replicated adjacency + incremental rowmax (LDS only) ----
        const float sjn_ = s_sjn;
        const int wbi = bi >> 6, wbj = bj >> 6;
        const unsigned long long mbi = 1ull << (bi & 63), mbj = 1ull << (bj & 63);
        {
            const int r = t;
            if (r == bj) {
                if (myAlive) { myAlive = false; rmax[t] = -INFINITY; }
            } else if (r == bi) {
                // rebuild own row = (row_bi | row_bj) minus {bi,bj}; sole writer of row bi
#pragma unroll
                for (int wq = 0; wq < 8; wq++) {
                    unsigned long long nw = AdjL[wq * 512 + bi] | AdjL[wq * 512 + bj];
                    if (wq == wbi) nw &= ~mbi;
                    if (wq == wbj) nw &= ~mbj;
                    AdjL[wq * 512 + bi] = nw;
                }
                int slot = atomicAdd(&nresc, 1); rescanList[slot] = bi;
            } else if (myAlive) {
                unsigned long long wi = AdjL[wbi * 512 + r];
                unsigned long long wj = (wbj == wbi) ? wi : AdjL[wbj * 512 + r];
                const bool nb = ((wi & mbi) | (wj & mbj)) != 0ull;
                if (wbi == wbj) {
                    AdjL[wbi * 512 + r] = (wi & ~(mbi | mbj)) | (nb ? mbi : 0ull);
                } else {
                    AdjL[wbi * 512 + r] = (wi & ~mbi) | (nb ? mbi : 0ull);
                    AdjL[wbj * 512 + r] = wj & ~mbj;
                }
                const int ra = rarg[t];
                if (ra == bi || ra == bj) {
                    int slot = atomicAdd(&nresc, 1); rescanList[slot] = r;
                } else if (nb) {
                    const float val = SIl[r] + sjn_ + c0;
                    if (val > rmax[t] || (val == rmax[t] && bi < ra)) { rmax[t] = val; rarg[t] = bi; }
                }
            }
        }
        __syncthreads();
        const int nr = nresc;
        for (int q = 0; q < nr; q++) {
            const int r = rescanList[q];
            const float sir = SIl[r];
            const unsigned long long word = AdjL[(t >> 6) * 512 + r];   // wave-broadcast
            float bv2 = ((word >> (t & 63)) & 1ull) ? (sir + SJl[t] + c0) : -INFINITY;
            int bc2 = t;
#pragma unroll
            for (int off = 32; off; off >>= 1) {
                float ov = __shfl_down(bv2, off, 64);
                int   ok = __shfl_down(bc2, off, 64);
                if (ov > bv2 || (ov == bv2 && ok < bc2)) { bv2 = ov; bc2 = ok; }
            }
            if ((t & 63) == 0) { wsv[t >> 6] = bv2; wsk[t >> 6] = bc2; }
            __syncthreads();
            if (t < 64) {
                float fv = (t < 8) ? wsv[t] : -INFINITY;
                int   fk = (t < 8) ? wsk[t] : 0x7fffffff;
#pragma unroll
                for (int off = 4; off; off >>= 1) {
                    float ov = __shfl_down(fv, off, 64);
                    int   ok = __shfl_down(fk, off, 64);
                    if (ov > fv || (ov == fv && ok < fk)) { fv = ov; fk = ok; }
                }
                if (t == 0) { rmax[r] = fv; rarg[r] = fk; }
            }
            __syncthreads();
        }
    }
    if (g == 0 && t == 0) out[b] = tot;
}

extern "C" void kernel_launch(void* const* d_in, const int* in_sizes, int n_in,
                              void* d_out, int out_size, void* d_ws, size_t ws_size,
                              hipStream_t stream) {
    const int*   token_ids = (const int*)d_in[0];
    const float* vocab_emb = (const float*)d_in[1];
    const float* pos_W     = (const float*)d_in[2];
    const float* pos_b     = (const float*)d_in[3];
    const float* W1        = (const float*)d_in[4];
    const float* b1        = (const float*)d_in[5];
    const float* w2        = (const float*)d_in[6];
    const float* b2        = (const float*)d_in[7];
    float* out = (float*)d_out;
    char*  ws  = (char*)d_ws;

    k1_uvc<<<1026, 256, 0, stream>>>(W1, b1, w2, b2, ws);
    k1b_proj<<<1025, 256, 0, stream>>>(W1, b1, ws);
    k2_feat<<<cB * cS, 256, 0, stream>>>(token_ids, vocab_emb, ws);
    k3_cls<<<cB * cS, 64, 0, stream>>>(pos_W, pos_b, ws);
    k4_adj<<<cB * cS, 256, 0, stream>>>(ws);

    // cooperative launch for the co-residency guarantee (custom split barrier inside)
    void* args[] = { (void*)&W1, (void*)&b1, (void*)&ws, (void*)&out };
    hipLaunchCooperativeKernel((void*)parse_main, dim3(cB * cG), dim3(cT),
                               args, 0, stream);
}

// Round 4
// 4493.044 us; speedup vs baseline: 3.0511x; 3.0511x over previous
//
#include <hip/hip_runtime.h>

#define cB 16
#define cS 512
#define cD 512
#define cL 64
#define cG 8     // blocks per batch
#define cT 512   // threads per block

// ---------------- workspace layout (bytes) ----------------
constexpr size_t FCOPY   = (size_t)cB * cS * cD * 4;            // 16 MB per F copy
constexpr size_t OFF_F0  = 0;
constexpr size_t OFF_F1  = FCOPY;
constexpr size_t OFF_U   = 2 * FCOPY;                           // D f32
constexpr size_t OFF_V   = OFF_U  + 2048;
constexpr size_t OFF_UA  = OFF_V  + 2048;                       // W1a @ u
constexpr size_t OFF_UB  = OFF_UA + 2048;                       // W1b @ u
constexpr size_t OFF_VA  = OFF_UB + 2048;                       // W1a @ v
constexpr size_t OFF_VB  = OFF_VA + 2048;                       // W1b @ v
constexpr size_t OFF_SC  = OFF_VB + 2048;                       // [c0, cu, cv]
constexpr size_t OFF_SI  = OFF_SC + 64;                         // B*S f32
constexpr size_t OFF_SJ  = OFF_SI + (size_t)cB*cS*4;
constexpr size_t OFF_CLS = OFF_SJ + (size_t)cB*cS*4;
constexpr size_t OFF_ADJ = OFF_CLS+ (size_t)cB*cS*4;            // B*S*8 u64 (row-major)
constexpr size_t OFF_RM  = OFF_ADJ+ (size_t)cB*cS*64;
constexpr size_t OFF_RA  = OFF_RM + (size_t)cB*cS*4;
constexpr size_t OFF_BAR = ((OFF_RA + (size_t)cB*cS*4 + 127) & ~(size_t)127);  // prog[16][8] u32 (128B stride/batch)

// ---------------- K1: u = W1a@w2, v = W1b@w2, c0 = b1@w2 + b2 ----------------
__global__ void k1_uvc(const float* __restrict__ W1, const float* __restrict__ b1,
                       const float* __restrict__ w2, const float* __restrict__ b2,
                       char* __restrict__ ws) {
    const int t = threadIdx.x;
    const int r = blockIdx.x;
    if (r == 1025) {   // zero progress counters (ws poisoned 0xAA pre-launch)
        unsigned* bar = (unsigned*)(ws + OFF_BAR);
        bar[t] = 0u; bar[t + 256] = 0u;
        return;
    }
    __shared__ float rs[256];
    float acc;
    if (r < 1024) {
        const float* row = W1 + (size_t)r * cD;
        acc = row[t] * w2[t] + row[t + 256] * w2[t + 256];
    } else {
        acc = b1[t] * w2[t] + b1[t + 256] * w2[t + 256];
    }
    rs[t] = acc; __syncthreads();
    for (int o = 128; o; o >>= 1) { if (t < o) rs[t] += rs[t + o]; __syncthreads(); }
    if (t == 0) {
        if (r < 512)        ((float*)(ws + OFF_U))[r] = rs[0];
        else if (r < 1024)  ((float*)(ws + OFF_V))[r - 512] = rs[0];
        else                ((float*)(ws + OFF_SC))[0] = rs[0] + b2[0];   // c0
    }
}

// ---------------- K1b: ua/ub/va/vb = W1{a,b} @ {u,v};  cu = b1·u, cv = b1·v --------
__global__ void k1b_proj(const float* __restrict__ W1, const float* __restrict__ b1,
                         char* __restrict__ ws) {
    __shared__ float ru[256], rv[256];
    const int t = threadIdx.x;
    const int k = blockIdx.x;
    const float* U = (const float*)(ws + OFF_U);
    const float* V = (const float*)(ws + OFF_V);
    const float* row = (k < 1024) ? (W1 + (size_t)k * cD) : b1;
    ru[t] = row[t] * U[t] + row[t + 256] * U[t + 256];
    rv[t] = row[t] * V[t] + row[t + 256] * V[t + 256];
    __syncthreads();
    for (int o = 128; o; o >>= 1) {
        if (t < o) { ru[t] += ru[t + o]; rv[t] += rv[t + o]; }
        __syncthreads();
    }
    if (t == 0) {
        if (k < 512)       { ((float*)(ws + OFF_UA))[k] = ru[0]; ((float*)(ws + OFF_VA))[k] = rv[0]; }
        else if (k < 1024) { ((float*)(ws + OFF_UB))[k - 512] = ru[0]; ((float*)(ws + OFF_VB))[k - 512] = rv[0]; }
        else               { ((float*)(ws + OFF_SC))[1] = ru[0]; ((float*)(ws + OFF_SC))[2] = rv[0]; }
    }
}

// ---------------- K2: gather feats into F copy0, si = f@u, sj = f@v ----------------
__global__ void k2_feat(const int* __restrict__ tok, const float* __restrict__ emb,
                        char* __restrict__ ws) {
    __shared__ float ru[256], rv[256];
    const int t = threadIdx.x;
    const int bs = blockIdx.x;
    const float* U = (const float*)(ws + OFF_U);
    const float* V = (const float*)(ws + OFF_V);
    float* F = (float*)(ws + OFF_F0);
    const int tk = tok[bs];
    const float* src = emb + (size_t)tk * cD;
    float* dst = F + (size_t)bs * cD;
    const float e0 = src[t], e1 = src[t + 256];
    dst[t] = e0; dst[t + 256] = e1;
    ru[t] = e0 * U[t] + e1 * U[t + 256];
    rv[t] = e0 * V[t] + e1 * V[t + 256];
    __syncthreads();
    for (int o = 128; o; o >>= 1) {
        if (t < o) { ru[t] += ru[t + o]; rv[t] += rv[t + o]; }
        __syncthreads();
    }
    if (t == 0) {
        ((float*)(ws + OFF_SI))[bs] = ru[0];
        ((float*)(ws + OFF_SJ))[bs] = rv[0];
    }
}

// ---------------- K3: logits argmax -> cls ----------------
__global__ void k3_cls(const float* __restrict__ posW, const float* __restrict__ posb,
                       char* __restrict__ ws) {
    const int t = threadIdx.x;            // one wave
    const int bs = blockIdx.x;
    const float* frow = (const float*)(ws + OFF_F0) + (size_t)bs * cD;
    float acc = posb[t];
    for (int k = 0; k < cD; k++) acc += frow[k] * posW[(size_t)k * cL + t];
    int idx = t;
    for (int off = 32; off; off >>= 1) {
        float ov = __shfl_down(acc, off, 64);
        int   oi = __shfl_down(idx, off, 64);
        if (ov > acc || (ov == acc && oi < idx)) { acc = ov; idx = oi; }
    }
    if (t == 0) ((int*)(ws + OFF_CLS))[bs] = idx;
}

// ---------------- K4: adjacency bitmask + initial per-row max ----------------
__global__ void k4_adj(char* __restrict__ ws) {
    __shared__ float rsv[256]; __shared__ int rsk[256];
    const int t = threadIdx.x;
    const int bs = blockIdx.x;
    const int b = bs >> 9, r = bs & 511;
    const int* cls = (const int*)(ws + OFF_CLS) + (size_t)b * cS;
    const float* SJ = (const float*)(ws + OFF_SJ) + (size_t)b * cS;
    const float sir = ((const float*)(ws + OFF_SI))[bs];
    const float c0 = ((const float*)(ws + OFF_SC))[0];
    unsigned long long* adjrow = (unsigned long long*)(ws + OFF_ADJ) + (size_t)bs * 8;
    const int cr = cls[r];
    float bv = -INFINITY; int bc = 0;
    for (int p = 0; p < 2; p++) {
        const int c = p * 256 + t;
        int dd = c - r; if (dd < 0) dd = -dd;
        const bool allowed = (c != r) && (dd == 1 || cls[c] == cr);
        unsigned long long m = __ballot(allowed);
        if ((t & 63) == 0) adjrow[p * 4 + (t >> 6)] = m;
        if (allowed) {
            float val = sir + SJ[c] + c0;
            if (val > bv || (val == bv && c < bc)) { bv = val; bc = c; }
        }
    }
    rsv[t] = bv; rsk[t] = bc; __syncthreads();
    for (int o = 128; o; o >>= 1) {
        if (t < o) {
            float s2 = rsv[t + o]; int k2 = rsk[t + o];
            if (s2 > rsv[t] || (s2 == rsv[t] && k2 < rsk[t])) { rsv[t] = s2; rsk[t] = k2; }
        }
        __syncthreads();
    }
    if (t == 0) { ((float*)(ws + OFF_RM))[bs] = rsv[0]; ((int*)(ws + OFF_RA))[bs] = rsk[0]; }
}

// ---------------- K5: parser — replicated LDS state, dependency-tracked waits ------
__global__ void __launch_bounds__(cT, 2)
parse_main(const float* __restrict__ W1, const float* __restrict__ b1,
           char* __restrict__ ws, float* __restrict__ out) {
    const int t = threadIdx.x;
    const int b = blockIdx.x & 15;        // batch
    const int g = blockIdx.x >> 4;        // 0..7
    const int d0 = g * 64;

    unsigned long long* F64[2] = {
        (unsigned long long*)(ws + OFF_F0) + (size_t)b * cS * cD / 2,
        (unsigned long long*)(ws + OFF_F1) + (size_t)b * cS * cD / 2 };
    unsigned* prog = (unsigned*)(ws + OFF_BAR) + (size_t)b * 32;   // prog[0..7]
    const float* SCp = (const float*)(ws + OFF_SC);
    const float c0 = SCp[0], cu = SCp[1], cv = SCp[2];

    // replicated per-block state
    __shared__ unsigned long long AdjL[8 * 512];   // column-major: AdjL[w*512 + r]
    __shared__ float SIl[512], SJl[512], rmax[512];
    __shared__ int   rarg[512];
    __shared__ int   tau[512];                     // last merge step of row r (-1 = never)
    __shared__ unsigned char par[512];             // F-copy parity per row
    __shared__ float xls[1024];                    // [fi(512); fj(512)]
    __shared__ float rsh[512];
    __shared__ float wsv[8];  __shared__ int wsk[8];
    __shared__ float ws_si[8], ws_sj[8];
    __shared__ int   s_bi, s_bj; __shared__ float s_bv, s_sin, s_sjn;
    __shared__ int   rescanList[516]; __shared__ int nresc;

    // W1 slice in registers: thread (ks=t>>6, od=t&63) holds W1[ks*128 .. +127][d0+od]
    const int ks = t >> 6, od = t & 63, kbase = ks * 128;
    float w[128];
#pragma unroll
    for (int kk = 0; kk < 128; kk++) w[kk] = W1[(size_t)(kk + kbase) * cD + d0 + od];

    // replicated init
    SIl[t]  = ((const float*)(ws + OFF_SI))[b * cS + t];
    SJl[t]  = ((const float*)(ws + OFF_SJ))[b * cS + t];
    rmax[t] = ((const float*)(ws + OFF_RM))[b * cS + t];
    rarg[t] = ((const int*)(ws + OFF_RA))[b * cS + t];
    tau[t]  = -1;
    par[t]  = 0;
    const float rua = ((const float*)(ws + OFF_UA))[t];
    const float rub = ((const float*)(ws + OFF_UB))[t];
    const float rva = ((const float*)(ws + OFF_VA))[t];
    const float rvb = ((const float*)(ws + OFF_VB))[t];
    float b1a = 0.f, b1b = 0.f;
    if (t < 32) { b1a = b1[d0 + 2 * t]; b1b = b1[d0 + 2 * t + 1]; }
    {
        const unsigned long long* AG =
            (const unsigned long long*)(ws + OFF_ADJ) + (size_t)b * cS * 8;
#pragma unroll
        for (int wq = 0; wq < 8; wq++) AdjL[wq * 512 + t] = AG[(size_t)t * 8 + wq];
    }
    bool myAlive = true;
    float tot = 0.f;
    __syncthreads();

    for (int it = 0; it < cS - 1; ++it) {
        // ---- A: replicated global argmax (LDS only) ----
        {
            float av = rmax[t]; int ak = (t << 9) | (rarg[t] & 511);
#pragma unroll
            for (int off = 32; off; off >>= 1) {
                float ov = __shfl_down(av, off, 64);
                int   ok = __shfl_down(ak, off, 64);
                if (ov > av || (ov == av && ok < ak)) { av = ov; ak = ok; }
            }
            if ((t & 63) == 0) { wsv[t >> 6] = av; wsk[t >> 6] = ak; }
        }
        __syncthreads();
        if (t < 64) {
            float fv = (t < 8) ? wsv[t] : -INFINITY;
            int   fk = (t < 8) ? wsk[t] : 0x7fffffff;
#pragma unroll
            for (int off = 4; off; off >>= 1) {
                float ov = __shfl_down(fv, off, 64);
                int   ok = __shfl_down(fk, off, 64);
                if (ov > fv || (ov == fv && ok < fk)) { fv = ov; fk = ok; }
            }
            if (t == 0) { s_bv = fv; s_bi = fk >> 9; s_bj = fk & 511; }
        }
        // ---- dependency-tracked wait: only if a needed F-row version is too fresh ----
        if (t == 0) {
            const int ti = tau[s_bi], tj = tau[s_bj];
            const int need = (ti > tj ? ti : tj) + 1;   // steps that must be fully stored
            if (need > 0) {
                const unsigned un = (unsigned)need;
                for (;;) {
                    unsigned mn = 0xffffffffu;
#pragma unroll
                    for (int q = 0; q < 8; q++) {
                        unsigned v = __hip_atomic_load(prog + q, __ATOMIC_RELAXED,
                                                       __HIP_MEMORY_SCOPE_AGENT);
                        if (v < mn) mn = v;
                    }
                    if (mn >= un) break;
                    __builtin_amdgcn_s_sleep(1);
                }
            }
        }
        __syncthreads();
        const int bi = s_bi, bj = s_bj;
        if (g == 0 && t == 0) {
            tot += s_bv;
            out[16 + b * 1022 + it * 2 + 0] = (float)bi;
            out[16 + b * 1022 + it * 2 + 1] = (float)bj;
        }

        // ---- C: load fi/fj (sc1 atomics, current copies), matvec, store slice ----
        const int pi = par[bi], pj = par[bj];
        if (t < 256) {
            unsigned long long x = __hip_atomic_load(F64[pi] + (size_t)bi * 256 + t,
                                    __ATOMIC_RELAXED, __HIP_MEMORY_SCOPE_AGENT);
            float2 f; __builtin_memcpy(&f, &x, 8);
            xls[2 * t] = f.x; xls[2 * t + 1] = f.y;
        } else {
            const int tt = t - 256;
            unsigned long long x = __hip_atomic_load(F64[pj] + (size_t)bj * 256 + tt,
                                    __ATOMIC_RELAXED, __HIP_MEMORY_SCOPE_AGENT);
            float2 f; __builtin_memcpy(&f, &x, 8);
            xls[512 + 2 * tt] = f.x; xls[513 + 2 * tt] = f.y;
        }
        __syncthreads();

        // sin/sjn (identical in all blocks) + W1 matvec partials
        {
            float csi = xls[t] * rua + xls[512 + t] * rub;
            float csj = xls[t] * rva + xls[512 + t] * rvb;
#pragma unroll
            for (int off = 32; off; off >>= 1) {
                csi += __shfl_down(csi, off, 64);
                csj += __shfl_down(csj, off, 64);
            }
            if ((t & 63) == 0) { ws_si[t >> 6] = csi; ws_sj[t >> 6] = csj; }
        }
        float acc = 0.f;
#pragma unroll
        for (int kk = 0; kk < 128; kk++) acc += w[kk] * xls[kbase + kk];
        rsh[t] = acc;
        __syncthreads();
        if (t < 32) {
            float p0 = b1a, p1 = b1b;
#pragma unroll
            for (int q = 0; q < 8; q++) { p0 += rsh[q * 64 + 2 * t]; p1 += rsh[q * 64 + 2 * t + 1]; }
            float2 pp; pp.x = p0; pp.y = p1;
            unsigned long long pk; __builtin_memcpy(&pk, &pp, 8);
            __hip_atomic_store(F64[pi ^ 1] + (size_t)bi * 256 + g * 32 + t, pk,
                               __ATOMIC_RELAXED, __HIP_MEMORY_SCOPE_AGENT);
        }
        if (t < 64) {
            float su = (t < 8) ? ws_si[t] : 0.f;
            float sv = (t < 8) ? ws_sj[t] : 0.f;
#pragma unroll
            for (int off = 4; off; off >>= 1) {
                su += __shfl_down(su, off, 64);
                sv += __shfl_down(sv, off, 64);
            }
            if (t == 0) {
                const float sn = su + cu, jn = sv + cv;
                s_sin = sn; s_sjn = jn;
                SIl[bi] = sn; SJl[bi] = jn;
                par[bi] ^= 1;
                tau[bi] = it;
                nresc = 0;
            }
        }
        // ---- publish progress: drain own slice stores (wave 0), then prog[g]=it+1 ----
        asm volatile("s_waitcnt vmcnt(0)" ::: "memory");
        if (t == 0)
            __hip_atomic_store(prog + g, (unsigned)(it + 1), __ATOMIC_RELAXED,
                               __HIP_MEMORY_SCOPE_AGENT);
        __syncthreads();

        // ---- D: replicated adjacency + incremental rowmax (LDS only) ----
        const float sjn_ = s_sjn;
        const int wbi = bi >> 6, wbj = bj >> 6;
        const unsigned long long mbi = 1ull << (bi & 63), mbj = 1ull << (bj & 63);
        {
            const int r = t;
            if (r == bj) {
                if (myAlive) { myAlive = false; rmax[t] = -INFINITY; }
            } else if (r == bi) {
                // rebuild own row = (row_bi | row_bj) minus {bi,bj}
#pragma unroll
                for (int wq = 0; wq < 8; wq++) {
                    unsigned long long nw = AdjL[wq * 512 + bi] | AdjL[wq * 512 + bj];
                    if (wq == wbi) nw &= ~mbi;
                    if (wq == wbj) nw &= ~mbj;
                    AdjL[wq * 512 + bi] = nw;
                }
                int slot = atomicAdd(&nresc, 1); rescanList[slot] = bi;
            } else if (myAlive) {
                unsigned long long wi = AdjL[wbi * 512 + r];
                unsigned long long wj = (wbj == wbi) ? wi : AdjL[wbj * 512 + r];
                const bool nb = ((wi & mbi) | (wj & mbj)) != 0ull;
                if (wbi == wbj) {
                    AdjL[wbi * 512 + r] = (wi & ~(mbi | mbj)) | (nb ? mbi : 0ull);
                } else {
                    AdjL[wbi * 512 + r] = (wi & ~mbi) | (nb ? mbi : 0ull);
                    AdjL[wbj * 512 + r] = wj & ~mbj;
                }
                const int ra = rarg[t];
                if (ra == bi || ra == bj) {
                    int slot = atomicAdd(&nresc, 1); rescanList[slot] = r;
                } else if (nb) {
                    const float val = SIl[r] + sjn_ + c0;
                    if (val > rmax[t] || (val == rmax[t] && bi < ra)) { rmax[t] = val; rarg[t] = bi; }
                }
            }
        }
        __syncthreads();
        // ---- wave-parallel rescans: wave q handles rescanList[q], q += 8 ----
        const int nr = nresc;
        const int wv = t >> 6, ln = t & 63;
        for (int q = wv; q < nr; q += 8) {
            const int r = rescanList[q];
            const float sir = SIl[r];
            float bv2 = -INFINITY; int bc2 = 0x7fffffff;
#pragma unroll
            for (int k = 0; k < 8; k++) {
                const unsigned long long word = AdjL[k * 512 + r];   // wave-uniform
                if ((word >> ln) & 1ull) {
                    const int c = k * 64 + ln;
                    const float val = sir + SJl[c] + c0;
                    if (val > bv2 || (val == bv2 && c < bc2)) { bv2 = val; bc2 = c; }
                }
            }
#pragma unroll
            for (int off = 32; off; off >>= 1) {
                float ov = __shfl_down(bv2, off, 64);
                int   ok = __shfl_down(bc2, off, 64);
                if (ov > bv2 || (ov == bv2 && ok < bc2)) { bv2 = ov; bc2 = ok; }
            }
            if (ln == 0) { rmax[r] = bv2; rarg[r] = bc2; }
        }
        __syncthreads();
    }
    if (g == 0 && t == 0) out[b] = tot;
}

extern "C" void kernel_launch(void* const* d_in, const int* in_sizes, int n_in,
                              void* d_out, int out_size, void* d_ws, size_t ws_size,
                              hipStream_t stream) {
    const int*   token_ids = (const int*)d_in[0];
    const float* vocab_emb = (const float*)d_in[1];
    const float* pos_W     = (const float*)d_in[2];
    const float* pos_b     = (const float*)d_in[3];
    const float* W1        = (const float*)d_in[4];
    const float* b1        = (const float*)d_in[5];
    const float* w2        = (const float*)d_in[6];
    const float* b2        = (const float*)d_in[7];
    float* out = (float*)d_out;
    char*  ws  = (char*)d_ws;

    k1_uvc<<<1026, 256, 0, stream>>>(W1, b1, w2, b2, ws);
    k1b_proj<<<1025, 256, 0, stream>>>(W1, b1, ws);
    k2_feat<<<cB * cS, 256, 0, stream>>>(token_ids, vocab_emb, ws);
    k3_cls<<<cB * cS, 64, 0, stream>>>(pos_W, pos_b, ws);
    k4_adj<<<cB * cS, 256, 0, stream>>>(ws);

    // cooperative launch for the co-residency guarantee (custom waits inside)
    void* args[] = { (void*)&W1, (void*)&b1, (void*)&ws, (void*)&out };
    hipLaunchCooperativeKernel((void*)parse_main, dim3(cB * cG), dim3(cT),
                               args, 0, stream);
}

// Round 6
// 4289.736 us; speedup vs baseline: 3.1957x; 1.0474x over previous
//
#include <hip/hip_runtime.h>

#define cB 16
#define cS 512
#define cD 512
#define cL 64
#define cG 8     // blocks per batch
#define cT 512   // threads per block

// ---------------- workspace layout (bytes) ----------------
constexpr size_t FCOPY   = (size_t)cB * cS * cD * 4;            // 16 MB per F copy
constexpr size_t OFF_F0  = 0;
constexpr size_t OFF_F1  = FCOPY;
constexpr size_t OFF_U   = 2 * FCOPY;                           // D f32
constexpr size_t OFF_V   = OFF_U  + 2048;
constexpr size_t OFF_UA  = OFF_V  + 2048;                       // W1a @ u
constexpr size_t OFF_UB  = OFF_UA + 2048;                       // W1b @ u
constexpr size_t OFF_VA  = OFF_UB + 2048;                       // W1a @ v
constexpr size_t OFF_VB  = OFF_VA + 2048;                       // W1b @ v
constexpr size_t OFF_SC  = OFF_VB + 2048;                       // [c0, cu, cv]
constexpr size_t OFF_SI  = OFF_SC + 64;                         // B*S f32
constexpr size_t OFF_SJ  = OFF_SI + (size_t)cB*cS*4;
constexpr size_t OFF_CLS = OFF_SJ + (size_t)cB*cS*4;
constexpr size_t OFF_ADJ = OFF_CLS+ (size_t)cB*cS*4;            // B*S*8 u64 (row-major)
constexpr size_t OFF_RM  = OFF_ADJ+ (size_t)cB*cS*64;
constexpr size_t OFF_RA  = OFF_RM + (size_t)cB*cS*4;
// prog: per batch 8 counters at 128B stride (no false sharing). 16 KB total.
constexpr size_t OFF_BAR = ((OFF_RA + (size_t)cB*cS*4 + 127) & ~(size_t)127);

// ---------------- K1: u = W1a@w2, v = W1b@w2, c0 = b1@w2 + b2 ----------------
__global__ void k1_uvc(const float* __restrict__ W1, const float* __restrict__ b1,
                       const float* __restrict__ w2, const float* __restrict__ b2,
                       char* __restrict__ ws) {
    const int t = threadIdx.x;
    const int r = blockIdx.x;
    if (r == 1025) {   // zero progress counters (ws poisoned 0xAA pre-launch)
        unsigned* bar = (unsigned*)(ws + OFF_BAR);
        for (int i = t; i < 4096; i += 256) bar[i] = 0u;
        return;
    }
    __shared__ float rs[256];
    float acc;
    if (r < 1024) {
        const float* row = W1 + (size_t)r * cD;
        acc = row[t] * w2[t] + row[t + 256] * w2[t + 256];
    } else {
        acc = b1[t] * w2[t] + b1[t + 256] * w2[t + 256];
    }
    rs[t] = acc; __syncthreads();
    for (int o = 128; o; o >>= 1) { if (t < o) rs[t] += rs[t + o]; __syncthreads(); }
    if (t == 0) {
        if (r < 512)        ((float*)(ws + OFF_U))[r] = rs[0];
        else if (r < 1024)  ((float*)(ws + OFF_V))[r - 512] = rs[0];
        else                ((float*)(ws + OFF_SC))[0] = rs[0] + b2[0];   // c0
    }
}

// ---------------- K1b: ua/ub/va/vb = W1{a,b} @ {u,v};  cu = b1·u, cv = b1·v --------
__global__ void k1b_proj(const float* __restrict__ W1, const float* __restrict__ b1,
                         char* __restrict__ ws) {
    __shared__ float ru[256], rv[256];
    const int t = threadIdx.x;
    const int k = blockIdx.x;
    const float* U = (const float*)(ws + OFF_U);
    const float* V = (const float*)(ws + OFF_V);
    const float* row = (k < 1024) ? (W1 + (size_t)k * cD) : b1;
    ru[t] = row[t] * U[t] + row[t + 256] * U[t + 256];
    rv[t] = row[t] * V[t] + row[t + 256] * V[t + 256];
    __syncthreads();
    for (int o = 128; o; o >>= 1) {
        if (t < o) { ru[t] += ru[t + o]; rv[t] += rv[t + o]; }
        __syncthreads();
    }
    if (t == 0) {
        if (k < 512)       { ((float*)(ws + OFF_UA))[k] = ru[0]; ((float*)(ws + OFF_VA))[k] = rv[0]; }
        else if (k < 1024) { ((float*)(ws + OFF_UB))[k - 512] = ru[0]; ((float*)(ws + OFF_VB))[k - 512] = rv[0]; }
        else               { ((float*)(ws + OFF_SC))[1] = ru[0]; ((float*)(ws + OFF_SC))[2] = rv[0]; }
    }
}

// ---------------- K2: gather feats into F copy0, si = f@u, sj = f@v ----------------
__global__ void k2_feat(const int* __restrict__ tok, const float* __restrict__ emb,
                        char* __restrict__ ws) {
    __shared__ float ru[256], rv[256];
    const int t = threadIdx.x;
    const int bs = blockIdx.x;
    const float* U = (const float*)(ws + OFF_U);
    const float* V = (const float*)(ws + OFF_V);
    float* F = (float*)(ws + OFF_F0);
    const int tk = tok[bs];
    const float* src = emb + (size_t)tk * cD;
    float* dst = F + (size_t)bs * cD;
    const float e0 = src[t], e1 = src[t + 256];
    dst[t] = e0; dst[t + 256] = e1;
    ru[t] = e0 * U[t] + e1 * U[t + 256];
    rv[t] = e0 * V[t] + e1 * V[t + 256];
    __syncthreads();
    for (int o = 128; o; o >>= 1) {
        if (t < o) { ru[t] += ru[t + o]; rv[t] += rv[t + o]; }
        __syncthreads();
    }
    if (t == 0) {
        ((float*)(ws + OFF_SI))[bs] = ru[0];
        ((float*)(ws + OFF_SJ))[bs] = rv[0];
    }
}

// ---------------- K3: logits argmax -> cls ----------------
__global__ void k3_cls(const float* __restrict__ posW, const float* __restrict__ posb,
                       char* __restrict__ ws) {
    const int t = threadIdx.x;            // one wave
    const int bs = blockIdx.x;
    const float* frow = (const float*)(ws + OFF_F0) + (size_t)bs * cD;
    float acc = posb[t];
    for (int k = 0; k < cD; k++) acc += frow[k] * posW[(size_t)k * cL + t];
    int idx = t;
    for (int off = 32; off; off >>= 1) {
        float ov = __shfl_down(acc, off, 64);
        int   oi = __shfl_down(idx, off, 64);
        if (ov > acc || (ov == acc && oi < idx)) { acc = ov; idx = oi; }
    }
    if (t == 0) ((int*)(ws + OFF_CLS))[bs] = idx;
}

// ---------------- K4: adjacency bitmask + initial per-row max ----------------
__global__ void k4_adj(char* __restrict__ ws) {
    __shared__ float rsv[256]; __shared__ int rsk[256];
    const int t = threadIdx.x;
    const int bs = blockIdx.x;
    const int b = bs >> 9, r = bs & 511;
    const int* cls = (const int*)(ws + OFF_CLS) + (size_t)b * cS;
    const float* SJ = (const float*)(ws + OFF_SJ) + (size_t)b * cS;
    const float sir = ((const float*)(ws + OFF_SI))[bs];
    const float c0 = ((const float*)(ws + OFF_SC))[0];
    unsigned long long* adjrow = (unsigned long long*)(ws + OFF_ADJ) + (size_t)bs * 8;
    const int cr = cls[r];
    float bv = -INFINITY; int bc = 0;
    for (int p = 0; p < 2; p++) {
        const int c = p * 256 + t;
        int dd = c - r; if (dd < 0) dd = -dd;
        const bool allowed = (c != r) && (dd == 1 || cls[c] == cr);
        unsigned long long m = __ballot(allowed);
        if ((t & 63) == 0) adjrow[p * 4 + (t >> 6)] = m;
        if (allowed) {
            float val = sir + SJ[c] + c0;
            if (val > bv || (val == bv && c < bc)) { bv = val; bc = c; }
        }
    }
    rsv[t] = bv; rsk[t] = bc; __syncthreads();
    for (int o = 128; o; o >>= 1) {
        if (t < o) {
            float s2 = rsv[t + o]; int k2 = rsk[t + o];
            if (s2 > rsv[t] || (s2 == rsv[t] && k2 < rsk[t])) { rsv[t] = s2; rsk[t] = k2; }
        }
        __syncthreads();
    }
    if (t == 0) { ((float*)(ws + OFF_RM))[bs] = rsv[0]; ((int*)(ws + OFF_RA))[bs] = rsk[0]; }
}

// ---------------- K5: parser — replicated LDS state, trimmed serial path ------
__global__ void __launch_bounds__(cT, 2)
parse_main(const float* __restrict__ W1, const float* __restrict__ b1,
           char* __restrict__ ws, float* __restrict__ out) {
    const int t = threadIdx.x;
    const int b = blockIdx.x & 15;        // batch (8 blocks of a batch land on one XCD)
    const int g = blockIdx.x >> 4;        // 0..7
    const int d0 = g * 64;
    const int wv = t >> 6;                // wave id = ks group
    const int ln = t & 63;

    unsigned long long* F64[2] = {
        (unsigned long long*)(ws + OFF_F0) + (size_t)b * cS * cD / 2,
        (unsigned long long*)(ws + OFF_F1) + (size_t)b * cS * cD / 2 };
    unsigned* prog = (unsigned*)(ws + OFF_BAR) + (size_t)b * 256;   // counters at prog[g*32]
    const float* SCp = (const float*)(ws + OFF_SC);
    const float c0 = SCp[0], cu_c = SCp[1], cv_c = SCp[2];

    // replicated per-block state
    __shared__ unsigned long long AdjL[8 * 512];   // column-major: AdjL[w*512 + r]
    __shared__ float SIl[512], SJl[512], rmax[512];
    __shared__ int   rarg[512];
    __shared__ int   tau[512];                     // last merge step of row r (-1 = never)
    __shared__ unsigned char par[512];             // F-copy parity per row
    __shared__ __align__(16) float xls[1024];      // wave-private slices [128*wv ..)
    __shared__ float rsh[512];
    __shared__ float wsv[8];  __shared__ int wsk[8];
    __shared__ float ws_si[8], ws_sj[8];
    __shared__ int   s_bi, s_bj; __shared__ float s_sin, s_sjn;
    __shared__ int   rescanList[516]; __shared__ int nresc;

    // W1 slice in registers: thread (wv, ln) holds W1[wv*128 .. +127][d0+ln]
    const int kbase = wv * 128;
    float w[128];
#pragma unroll
    for (int kk = 0; kk < 128; kk++) w[kk] = W1[(size_t)(kk + kbase) * cD + d0 + ln];

    // csi/csj constants matching this thread's 2 staged floats (x index xk, xk+1)
    const int xk = (wv & 3) * 128 + 2 * ln;
    const float* cu_base = (const float*)(ws + ((wv < 4) ? OFF_UA : OFF_UB));
    const float* cvb     = (const float*)(ws + ((wv < 4) ? OFF_VA : OFF_VB));
    const float cu0 = cu_base[xk], cu1 = cu_base[xk + 1];
    const float cv0 = cvb[xk],     cv1 = cvb[xk + 1];

    // replicated init
    SIl[t]  = ((const float*)(ws + OFF_SI))[b * cS + t];
    SJl[t]  = ((const float*)(ws + OFF_SJ))[b * cS + t];
    rmax[t] = ((const float*)(ws + OFF_RM))[b * cS + t];
    rarg[t] = ((const int*)(ws + OFF_RA))[b * cS + t];
    tau[t]  = -1;
    par[t]  = 0;
    float b1a = 0.f, b1b = 0.f;
    if (t < 32) { b1a = b1[d0 + 2 * t]; b1b = b1[d0 + 2 * t + 1]; }
    {
        const unsigned long long* AG =
            (const unsigned long long*)(ws + OFF_ADJ) + (size_t)b * cS * 8;
#pragma unroll
        for (int wq = 0; wq < 8; wq++) AdjL[wq * 512 + t] = AG[(size_t)t * 8 + wq];
    }
    bool myAlive = true;
    float tot = 0.f;

    // initial per-wave rowmax reduce -> wsv/wsk
    {
        float av = rmax[t]; int ak = (t << 9) | (rarg[t] & 511);
#pragma unroll
        for (int off = 32; off; off >>= 1) {
            float ov = __shfl_down(av, off, 64);
            int   ok = __shfl_down(ak, off, 64);
            if (ov > av || (ov == av && ok < ak)) { av = ov; ak = ok; }
        }
        if (ln == 0) { wsv[wv] = av; wsk[wv] = ak; }
    }
    __syncthreads();   // B1

    for (int it = 0; it < cS - 1; ++it) {
        // ---- wave0: final argmax + dependency poll (no other waves involved) ----
        if (wv == 0) {
            float fv = (ln < 8) ? wsv[ln] : -INFINITY;
            int   fk = (ln < 8) ? wsk[ln] : 0x7fffffff;
#pragma unroll
            for (int off = 4; off; off >>= 1) {
                float ov = __shfl_down(fv, off, 64);
                int   ok = __shfl_down(fk, off, 64);
                if (ov > fv || (ov == fv && ok < fk)) { fv = ov; fk = ok; }
            }
            const int bk = __shfl(fk, 0, 64);
            const int pbi = bk >> 9, pbj = bk & 511;
            const int ti = tau[pbi], tj = tau[pbj];
            const int need = (ti > tj ? ti : tj) + 1;
            if (need > 0) {
                const unsigned un = (unsigned)need;
                for (;;) {
                    unsigned v = 0xffffffffu;
                    if (ln < 8) v = __hip_atomic_load(prog + ln * 32, __ATOMIC_RELAXED,
                                                      __HIP_MEMORY_SCOPE_AGENT);
                    if (__ballot(v >= un) == ~0ull) break;
                    __builtin_amdgcn_s_sleep(1);
                }
            }
            if (ln == 0) {
                s_bi = pbi; s_bj = pbj;
                if (g == 0) {
                    tot += fv;
                    out[16 + b * 1022 + it * 2 + 0] = (float)pbi;
                    out[16 + b * 1022 + it * 2 + 1] = (float)pbj;
                }
            }
        }
        __syncthreads();   // B2
        const int bi = s_bi, bj = s_bj;

        // ---- C: wave-local load + stage + matvec (no cross-wave dependency) ----
        const int myrow = (wv < 4) ? bi : bj;
        const int mypar = par[myrow];                  // wave-uniform LDS read
        unsigned long long xv = __hip_atomic_load(
            F64[mypar] + (size_t)myrow * 256 + (wv & 3) * 64 + ln,
            __ATOMIC_RELAXED, __HIP_MEMORY_SCOPE_AGENT);
        float2 f2; __builtin_memcpy(&f2, &xv, 8);
        ((float2*)xls)[64 * wv + ln] = f2;             // wave-private slice
        // csi/csj partials straight from registers
        {
            float csi = f2.x * cu0 + f2.y * cu1;
            float csj = f2.x * cv0 + f2.y * cv1;
#pragma unroll
            for (int off = 32; off; off >>= 1) {
                csi += __shfl_down(csi, off, 64);
                csj += __shfl_down(csj, off, 64);
            }
            if (ln == 0) { ws_si[wv] = csi; ws_sj[wv] = csj; }
        }
        // matvec on own slice (per-wave lgkmcnt ordering, no barrier needed)
        {
            const float4* x4 = (const float4*)xls + 32 * wv;
            float a0 = 0.f, a1 = 0.f, a2 = 0.f, a3 = 0.f;
#pragma unroll
            for (int m = 0; m < 32; m++) {
                const float4 q = x4[m];
                a0 += w[4 * m + 0] * q.x;
                a1 += w[4 * m + 1] * q.y;
                a2 += w[4 * m + 2] * q.z;
                a3 += w[4 * m + 3] * q.w;
            }
            rsh[t] = (a0 + a1) + (a2 + a3);
        }
        __syncthreads();   // B3

        // wave0: output reduce + store + drain + publish   |   wave1: sin/sjn reduce
        if (t < 32) {
            float p0 = b1a, p1 = b1b;
#pragma unroll
            for (int q = 0; q < 8; q++) { p0 += rsh[q * 64 + 2 * t]; p1 += rsh[q * 64 + 2 * t + 1]; }
            float2 pp; pp.x = p0; pp.y = p1;
            unsigned long long pk; __builtin_memcpy(&pk, &pp, 8);
            __hip_atomic_store(F64[mypar ^ 1] + (size_t)bi * 256 + g * 32 + t, pk,
                               __ATOMIC_RELAXED, __HIP_MEMORY_SCOPE_AGENT);
        }
        if (wv == 0) {
            asm volatile("s_waitcnt vmcnt(0)" ::: "memory");
            if (ln == 0)
                __hip_atomic_store(prog + g * 32, (unsigned)(it + 1), __ATOMIC_RELAXED,
                                   __HIP_MEMORY_SCOPE_AGENT);
        } else if (wv == 1) {
            float su = (ln < 8) ? ws_si[ln] : 0.f;
            float sv = (ln < 8) ? ws_sj[ln] : 0.f;
#pragma unroll
            for (int off = 4; off; off >>= 1) {
                su += __shfl_down(su, off, 64);
                sv += __shfl_down(sv, off, 64);
            }
            if (ln == 0) {
                const float sn = su + cu_c, jn = sv + cv_c;
                s_sin = sn; s_sjn = jn;
                SIl[bi] = sn; SJl[bi] = jn;
                par[bi] ^= 1;
                tau[bi] = it;
                nresc = 0;
            }
        }
        __syncthreads();   // B4

        // ---- D: replicated adjacency + incremental rowmax (LDS only) ----
        const float sjn_ = s_sjn;
        const int wbi = bi >> 6, wbj = bj >> 6;
        const unsigned long long mbi = 1ull << (bi & 63), mbj = 1ull << (bj & 63);
        {
            const int r = t;
            if (r == bj) {
                if (myAlive) { myAlive = false; rmax[t] = -INFINITY; }
            } else if (r == bi) {
                // rebuild own row = (row_bi | row_bj) minus {bi,bj}
#pragma unroll
                for (int wq = 0; wq < 8; wq++) {
                    unsigned long long nw = AdjL[wq * 512 + bi] | AdjL[wq * 512 + bj];
                    if (wq == wbi) nw &= ~mbi;
                    if (wq == wbj) nw &= ~mbj;
                    AdjL[wq * 512 + bi] = nw;
                }
                int slot = atomicAdd(&nresc, 1); rescanList[slot] = bi;
            } else if (myAlive) {
                unsigned long long wi = AdjL[wbi * 512 + r];
                unsigned long long wj = (wbj == wbi) ? wi : AdjL[wbj * 512 + r];
                const bool nb = ((wi & mbi) | (wj & mbj)) != 0ull;
                if (wbi == wbj) {
                    AdjL[wbi * 512 + r] = (wi & ~(mbi | mbj)) | (nb ? mbi : 0ull);
                } else {
                    AdjL[wbi * 512 + r] = (wi & ~mbi) | (nb ? mbi : 0ull);
                    AdjL[wbj * 512 + r] = wj & ~mbj;
                }
                const int ra = rarg[t];
                if (ra == bi || ra == bj) {
                    int slot = atomicAdd(&nresc, 1); rescanList[slot] = r;
                } else if (nb) {
                    const float val = SIl[r] + sjn_ + c0;
                    if (val > rmax[t] || (val == rmax[t] && bi < ra)) { rmax[t] = val; rarg[t] = bi; }
                }
            }
        }
        __syncthreads();   // B5
        // ---- wave-parallel rescans ----
        const int nr = nresc;
        for (int q = wv; q < nr; q += 8) {
            const int r = rescanList[q];
            const float sir = SIl[r];
            float bv2 = -INFINITY; int bc2 = 0x7fffffff;
#pragma unroll
            for (int k = 0; k < 8; k++) {
                const unsigned long long word = AdjL[k * 512 + r];   // wave-uniform
                if ((word >> ln) & 1ull) {
                    const int c = k * 64 + ln;
                    const float val = sir + SJl[c] + c0;
                    if (val > bv2 || (val == bv2 && c < bc2)) { bv2 = val; bc2 = c; }
                }
            }
#pragma unroll
            for (int off = 32; off; off >>= 1) {
                float ov = __shfl_down(bv2, off, 64);
                int   ok = __shfl_down(bc2, off, 64);
                if (ov > bv2 || (ov == bv2 && ok < bc2)) { bv2 = ov; bc2 = ok; }
            }
            if (ln == 0) { rmax[r] = bv2; rarg[r] = bc2; }
        }
        __syncthreads();   // B6
        // ---- fold next step's per-wave rowmax reduce here ----
        {
            float av = rmax[t]; int ak = (t << 9) | (rarg[t] & 511);
#pragma unroll
            for (int off = 32; off; off >>= 1) {
                float ov = __shfl_down(av, off, 64);
                int   ok = __shfl_down(ak, off, 64);
                if (ov > av || (ov == av && ok < ak)) { av = ov; ak = ok; }
            }
            if (ln == 0) { wsv[wv] = av; wsk[wv] = ak; }
        }
        __syncthreads();   // B1
    }
    if (g == 0 && t == 0) out[b] = tot;
}

extern "C" void kernel_launch(void* const* d_in, const int* in_sizes, int n_in,
                              void* d_out, int out_size, void* d_ws, size_t ws_size,
                              hipStream_t stream) {
    const int*   token_ids = (const int*)d_in[0];
    const float* vocab_emb = (const float*)d_in[1];
    const float* pos_W     = (const float*)d_in[2];
    const float* pos_b     = (const float*)d_in[3];
    const float* W1        = (const float*)d_in[4];
    const float* b1        = (const float*)d_in[5];
    const float* w2        = (const float*)d_in[6];
    const float* b2        = (const float*)d_in[7];
    float* out = (float*)d_out;
    char*  ws  = (char*)d_ws;

    k1_uvc<<<1026, 256, 0, stream>>>(W1, b1, w2, b2, ws);
    k1b_proj<<<1025, 256, 0, stream>>>(W1, b1, ws);
    k2_feat<<<cB * cS, 256, 0, stream>>>(token_ids, vocab_emb, ws);
    k3_cls<<<cB * cS, 64, 0, stream>>>(pos_W, pos_b, ws);
    k4_adj<<<cB * cS, 256, 0, stream>>>(ws);

    // cooperative launch for the co-residency guarantee (custom waits inside)
    void* args[] = { (void*)&W1, (void*)&b1, (void*)&ws, (void*)&out };
    hipLaunchCooperativeKernel((void*)parse_main, dim3(cB * cG), dim3(cT),
                               args, 0, stream);
}